// Round 1
// baseline (739.140 us; speedup 1.0000x reference)
//
#include <hip/hip_runtime.h>

#define KK 64
#define TT 1024
#define BB 256
#define START_TAG 0

__device__ __forceinline__ float lane_bcast(float v, int lane) {
    return __int_as_float(__builtin_amdgcn_readlane(__float_as_int(v), lane));
}

// Forward algorithm in the probability domain with per-step max renormalization.
// One wave (64 lanes) per batch element; lane i owns state i and holds
// exp(trans[i, :]) in 64 VGPRs. Broadcast of a[j] via v_readlane (no LDS).
__global__ __launch_bounds__(64) void crf_forward_kernel(
    const float* __restrict__ feats,
    const float* __restrict__ trans,
    const float* __restrict__ masks,
    float* __restrict__ fwd_out)
{
    const int b = blockIdx.x;
    const int i = threadIdx.x;

    // exp(transitions) row i into registers (exp(-10000) flushes to exactly 0,
    // matching the reference's exp(-10000 - max) -> 0 in fp32)
    float et[KK];
    const float* trow = trans + i * KK;
    #pragma unroll
    for (int j = 0; j < KK; ++j) et[j] = __expf(trow[j]);

    float a = (i == START_TAG) ? 1.0f : 0.0f;  // exp(alpha0)
    float offset = 0.0f;                        // running log-scale

    const float* fb = feats + (size_t)b * TT * KK;
    const float* mb = masks + (size_t)b * TT;

    for (int t = 1; t < TT; ++t) {
        float f  = fb[t * KK + i];
        float mk = mb[t];

        // a_new[i] = sum_j ET[i,j] * a[j]   (4 accumulators for ILP)
        float acc0 = 0.f, acc1 = 0.f, acc2 = 0.f, acc3 = 0.f;
        #pragma unroll
        for (int j = 0; j < KK; j += 4) {
            acc0 = fmaf(et[j+0], lane_bcast(a, j+0), acc0);
            acc1 = fmaf(et[j+1], lane_bcast(a, j+1), acc1);
            acc2 = fmaf(et[j+2], lane_bcast(a, j+2), acc2);
            acc3 = fmaf(et[j+3], lane_bcast(a, j+3), acc3);
        }
        float s    = (acc0 + acc1) + (acc2 + acc3);
        float anew = s * __expf(f);

        // wave-wide max for renormalization (always > 0: state START feeds all
        // states with positive weight except the dead START row/END col)
        float mx = anew;
        #pragma unroll
        for (int off = 32; off >= 1; off >>= 1)
            mx = fmaxf(mx, __shfl_xor(mx, off, 64));

        float a_next   = anew * __builtin_amdgcn_rcpf(mx);
        float off_next = offset + __logf(mx);

        // mask handling: mask==0 keeps alpha (given inputs have all-ones masks)
        bool upd = (mk != 0.0f);
        a      = upd ? a_next   : a;
        offset = upd ? off_next : offset;
    }

    // forward_score = log(sum_j exp(alpha_j)) = offset + log(sum_j a_j)
    float s = a;
    #pragma unroll
    for (int off = 32; off >= 1; off >>= 1)
        s += __shfl_xor(s, off, 64);
    if (i == 0) fwd_out[b] = offset + __logf(s);
}

// Gold score: sum_t (trans[tag_t, tag_{t-1}] + feats[b, t, tag_t]) * mask[b, t]
__global__ __launch_bounds__(256) void crf_gold_kernel(
    const float* __restrict__ feats,
    const float* __restrict__ trans,
    const int* __restrict__ tags,
    const float* __restrict__ masks,
    float* __restrict__ gold_out)
{
    const int b   = blockIdx.x;
    const int tid = threadIdx.x;
    const int*   tg = tags  + b * TT;
    const float* fb = feats + (size_t)b * TT * KK;
    const float* mb = masks + b * TT;

    float local = 0.f;
    for (int t = 1 + tid; t < TT; t += 256) {
        int ct = tg[t], pt = tg[t - 1];
        local += (trans[ct * KK + pt] + fb[t * KK + ct]) * mb[t];
    }
    #pragma unroll
    for (int off = 32; off >= 1; off >>= 1)
        local += __shfl_xor(local, off, 64);

    __shared__ float red[4];
    int wid = tid >> 6, lane = tid & 63;
    if (lane == 0) red[wid] = local;
    __syncthreads();
    if (tid == 0) gold_out[b] = (red[0] + red[1]) + (red[2] + red[3]);
}

__global__ __launch_bounds__(64) void crf_combine_kernel(
    const float* __restrict__ fwd,
    const float* __restrict__ gold,
    float* __restrict__ out)
{
    int l = threadIdx.x;
    float s = 0.f;
    #pragma unroll
    for (int k = 0; k < 4; ++k) {
        int b = l + k * 64;
        s += fwd[b] - gold[b];
    }
    #pragma unroll
    for (int off = 32; off >= 1; off >>= 1)
        s += __shfl_xor(s, off, 64);
    if (l == 0) out[0] = s * (1.0f / 256.0f);
}

extern "C" void kernel_launch(void* const* d_in, const int* in_sizes, int n_in,
                              void* d_out, int out_size, void* d_ws, size_t ws_size,
                              hipStream_t stream) {
    const float* feats = (const float*)d_in[0];
    const float* trans = (const float*)d_in[1];
    const int*   tags  = (const int*)d_in[2];
    const float* masks = (const float*)d_in[3];

    float* fwd  = (float*)d_ws;        // 256 floats
    float* gold = fwd + BB;            // 256 floats
    float* out  = (float*)d_out;

    crf_forward_kernel<<<BB, 64, 0, stream>>>(feats, trans, masks, fwd);
    crf_gold_kernel<<<BB, 256, 0, stream>>>(feats, trans, tags, masks, gold);
    crf_combine_kernel<<<1, 64, 0, stream>>>(fwd, gold, out);
}

// Round 2
// 505.965 us; speedup vs baseline: 1.4609x; 1.4609x over previous
//
#include <hip/hip_runtime.h>

#define KK 64
#define TT 1024
#define BB 256
#define START_TAG 0

__device__ __forceinline__ float lane_bcast(float v, int lane) {
    return __int_as_float(__builtin_amdgcn_readlane(__float_as_int(v), lane));
}

// Forward algorithm in the probability domain with periodic max renormalization.
// One wave (64 lanes) per batch element; lane i owns state i and holds
// exp(trans[i, :]) in 64 VGPRs (launch_bounds(64,1) -> 512-VGPR budget, no
// spill). Broadcast of a[j] via v_readlane (no LDS, no barriers).
// Renorm every 4 steps: per-step growth factor <= 64*e^3.5*e^4.6 ~ 2e5, so 4
// unnormalized steps stay < 1.6e21, far inside fp32 range.
// Gold score (gather-reduce) fused into the epilogue.
__global__ __launch_bounds__(64, 1) void crf_forward_kernel(
    const float* __restrict__ feats,
    const float* __restrict__ trans,
    const float* __restrict__ masks,
    const int*   __restrict__ tags,
    float* __restrict__ fwd_out)
{
    const int b = blockIdx.x;
    const int i = threadIdx.x;

    // exp(transitions) row i into registers (exp(-10000) flushes to exactly 0,
    // matching the reference's exp(-10000 - max) -> 0 in fp32)
    float et[KK];
    const float* trow = trans + i * KK;
    #pragma unroll
    for (int j = 0; j < KK; ++j) et[j] = __expf(trow[j]);

    float a = (i == START_TAG) ? 1.0f : 0.0f;  // exp(alpha0)
    float offset = 0.0f;                        // running log-scale

    const float* fb = feats + (size_t)b * TT * KK;
    const float* mb = masks + (size_t)b * TT;

    float f_cur = fb[1 * KK + i];   // prefetch t=1

    for (int t = 1; t < TT; ++t) {
        // software prefetch of next step's emission (hide global latency
        // behind the matvec)
        int tn = (t + 1 < TT) ? (t + 1) : t;
        float f_next = fb[tn * KK + i];
        float mk = mb[t];

        // a_new[i] = sum_j ET[i,j] * a[j]   (4 accumulators for ILP)
        float acc0 = 0.f, acc1 = 0.f, acc2 = 0.f, acc3 = 0.f;
        #pragma unroll
        for (int j = 0; j < KK; j += 4) {
            acc0 = fmaf(et[j+0], lane_bcast(a, j+0), acc0);
            acc1 = fmaf(et[j+1], lane_bcast(a, j+1), acc1);
            acc2 = fmaf(et[j+2], lane_bcast(a, j+2), acc2);
            acc3 = fmaf(et[j+3], lane_bcast(a, j+3), acc3);
        }
        float s    = (acc0 + acc1) + (acc2 + acc3);
        float anew = s * __expf(f_cur);

        // mask: mask==0 keeps previous alpha (same scale, offset unaffected)
        a = (mk != 0.0f) ? anew : a;

        // periodic renormalization (wave-uniform branch)
        if ((t & 3) == 0 || t == TT - 1) {
            float mx = a;
            #pragma unroll
            for (int off = 32; off >= 1; off >>= 1)
                mx = fmaxf(mx, __shfl_xor(mx, off, 64));
            // scale error of rcp folds into a and is recovered by the final
            // log(sum a) + offset, so no precision concern
            a = a * __builtin_amdgcn_rcpf(mx);
            offset += __logf(mx);
        }
        f_cur = f_next;
    }

    // forward_score = offset + log(sum_j a_j)
    float s = a;
    #pragma unroll
    for (int off = 32; off >= 1; off >>= 1)
        s += __shfl_xor(s, off, 64);
    float fwd_score = offset + __logf(s);

    // ---- fused gold score: sum_t (trans[ct,pt] + feats[t,ct]) * mask[t] ----
    const int* tg = tags + b * TT;
    float g = 0.f;
    for (int t = 1 + i; t < TT; t += 64) {
        int ct = tg[t], pt = tg[t - 1];
        g += (trans[ct * KK + pt] + fb[t * KK + ct]) * mb[t];
    }
    #pragma unroll
    for (int off = 32; off >= 1; off >>= 1)
        g += __shfl_xor(g, off, 64);

    if (i == 0) fwd_out[b] = fwd_score - g;
}

__global__ __launch_bounds__(64) void crf_combine_kernel(
    const float* __restrict__ diff,
    float* __restrict__ out)
{
    int l = threadIdx.x;
    float s = 0.f;
    #pragma unroll
    for (int k = 0; k < 4; ++k) s += diff[l + k * 64];
    #pragma unroll
    for (int off = 32; off >= 1; off >>= 1)
        s += __shfl_xor(s, off, 64);
    if (l == 0) out[0] = s * (1.0f / 256.0f);
}

extern "C" void kernel_launch(void* const* d_in, const int* in_sizes, int n_in,
                              void* d_out, int out_size, void* d_ws, size_t ws_size,
                              hipStream_t stream) {
    const float* feats = (const float*)d_in[0];
    const float* trans = (const float*)d_in[1];
    const int*   tags  = (const int*)d_in[2];
    const float* masks = (const float*)d_in[3];

    float* diff = (float*)d_ws;        // 256 floats: fwd - gold per batch
    float* out  = (float*)d_out;

    crf_forward_kernel<<<BB, 64, 0, stream>>>(feats, trans, masks, tags, diff);
    crf_combine_kernel<<<1, 64, 0, stream>>>(diff, out);
}

// Round 3
// 499.804 us; speedup vs baseline: 1.4789x; 1.0123x over previous
//
#include <hip/hip_runtime.h>

#define KK 64
#define TT 1024
#define BB 256
#define START_TAG 0

__device__ __forceinline__ float lane_bcast(float v, int lane) {
    return __int_as_float(__builtin_amdgcn_readlane(__float_as_int(v), lane));
}

// 64 explicitly named scalars so the ET row CANNOT be demoted to scratch.
#define DECL4(a,b,c,d) \
    float et##a = __expf(trow[a]); float et##b = __expf(trow[b]); \
    float et##c = __expf(trow[c]); float et##d = __expf(trow[d]);

#define FMA4(a,b,c,d) \
    acc0 = fmaf(et##a, lane_bcast(av, a), acc0); \
    acc1 = fmaf(et##b, lane_bcast(av, b), acc1); \
    acc2 = fmaf(et##c, lane_bcast(av, c), acc2); \
    acc3 = fmaf(et##d, lane_bcast(av, d), acc3);

// Forward algorithm in the probability domain, periodic max renormalization.
// One wave per batch element; lane i owns state i, holds exp(trans[i,:]) in
// 64 named VGPRs. Broadcast of a[j] via v_readlane (no LDS, no barriers).
// Renorm every 4 steps (per-step growth <= ~2^18, 4 steps < 2^72, safe fp32).
// Gold score fused into the epilogue.
__global__ __launch_bounds__(64, 1) void crf_forward_kernel(
    const float* __restrict__ feats,
    const float* __restrict__ trans,
    const float* __restrict__ masks,
    const int*   __restrict__ tags,
    float* __restrict__ fwd_out)
{
    const int b = blockIdx.x;
    const int i = threadIdx.x;

    const float* trow = trans + i * KK;
    DECL4(0,1,2,3)    DECL4(4,5,6,7)    DECL4(8,9,10,11)  DECL4(12,13,14,15)
    DECL4(16,17,18,19) DECL4(20,21,22,23) DECL4(24,25,26,27) DECL4(28,29,30,31)
    DECL4(32,33,34,35) DECL4(36,37,38,39) DECL4(40,41,42,43) DECL4(44,45,46,47)
    DECL4(48,49,50,51) DECL4(52,53,54,55) DECL4(56,57,58,59) DECL4(60,61,62,63)

    float a = (i == START_TAG) ? 1.0f : 0.0f;  // exp(alpha0)
    float offset = 0.0f;                        // running log-scale

    const float* fb = feats + (size_t)b * TT * KK;
    const float* mb = masks + (size_t)b * TT;

    float f_cur = fb[1 * KK + i];   // prefetch t=1

    for (int t = 1; t < TT; ++t) {
        int tn = (t + 1 < TT) ? (t + 1) : t;
        float f_next = fb[tn * KK + i];  // prefetch next emission
        float mk = mb[t];

        float av = a;
        float acc0 = 0.f, acc1 = 0.f, acc2 = 0.f, acc3 = 0.f;
        FMA4(0,1,2,3)    FMA4(4,5,6,7)    FMA4(8,9,10,11)  FMA4(12,13,14,15)
        FMA4(16,17,18,19) FMA4(20,21,22,23) FMA4(24,25,26,27) FMA4(28,29,30,31)
        FMA4(32,33,34,35) FMA4(36,37,38,39) FMA4(40,41,42,43) FMA4(44,45,46,47)
        FMA4(48,49,50,51) FMA4(52,53,54,55) FMA4(56,57,58,59) FMA4(60,61,62,63)

        float s    = (acc0 + acc1) + (acc2 + acc3);
        float anew = s * __expf(f_cur);

        // mask==0 keeps previous alpha (offset unaffected)
        a = (mk != 0.0f) ? anew : a;

        // periodic renormalization (wave-uniform branch)
        if ((t & 3) == 0 || t == TT - 1) {
            float mx = a;
            #pragma unroll
            for (int off = 32; off >= 1; off >>= 1)
                mx = fmaxf(mx, __shfl_xor(mx, off, 64));
            a = a * __builtin_amdgcn_rcpf(mx);
            offset += __logf(mx);
        }
        f_cur = f_next;
    }

    // forward_score = offset + log(sum_j a_j)
    float s = a;
    #pragma unroll
    for (int off = 32; off >= 1; off >>= 1)
        s += __shfl_xor(s, off, 64);
    float fwd_score = offset + __logf(s);

    // ---- fused gold score: sum_t (trans[ct,pt] + feats[t,ct]) * mask[t] ----
    const int* tg = tags + b * TT;
    float g = 0.f;
    for (int t = 1 + i; t < TT; t += 64) {
        int ct = tg[t], pt = tg[t - 1];
        g += (trans[ct * KK + pt] + fb[t * KK + ct]) * mb[t];
    }
    #pragma unroll
    for (int off = 32; off >= 1; off >>= 1)
        g += __shfl_xor(g, off, 64);

    if (i == 0) fwd_out[b] = fwd_score - g;
}

__global__ __launch_bounds__(64) void crf_combine_kernel(
    const float* __restrict__ diff,
    float* __restrict__ out)
{
    int l = threadIdx.x;
    float s = 0.f;
    #pragma unroll
    for (int k = 0; k < 4; ++k) s += diff[l + k * 64];
    #pragma unroll
    for (int off = 32; off >= 1; off >>= 1)
        s += __shfl_xor(s, off, 64);
    if (l == 0) out[0] = s * (1.0f / 256.0f);
}

extern "C" void kernel_launch(void* const* d_in, const int* in_sizes, int n_in,
                              void* d_out, int out_size, void* d_ws, size_t ws_size,
                              hipStream_t stream) {
    const float* feats = (const float*)d_in[0];
    const float* trans = (const float*)d_in[1];
    const int*   tags  = (const int*)d_in[2];
    const float* masks = (const float*)d_in[3];

    float* diff = (float*)d_ws;        // 256 floats: fwd - gold per batch
    float* out  = (float*)d_out;

    crf_forward_kernel<<<BB, 64, 0, stream>>>(feats, trans, masks, tags, diff);
    crf_combine_kernel<<<1, 64, 0, stream>>>(diff, out);
}

// Round 4
// 386.522 us; speedup vs baseline: 1.9123x; 1.2931x over previous
//
#include <hip/hip_runtime.h>

#define KK 64
#define TT 1024
#define BB 256
#define START_TAG 0

__device__ __forceinline__ float lane_bcast(float v, int lane) {
    return __int_as_float(__builtin_amdgcn_readlane(__float_as_int(v), lane));
}

// 64 named scalars for the exp(trans) row, PINNED into VGPRs with opaque asm
// so the compiler cannot rematerialize exp(load(trow[j])) inside the loop
// (round 2/3 pathology: VGPR_Count=52 proved et lived nowhere — remat per step).
#define DECL4(p,q,r,s) \
    float et##p = __expf(trow[p]), et##q = __expf(trow[q]), \
          et##r = __expf(trow[r]), et##s = __expf(trow[s]);

#define PIN4(p,q,r,s) \
    asm volatile("" : "+v"(et##p), "+v"(et##q), "+v"(et##r), "+v"(et##s));

// Batch 4 readlanes ahead of their 4 FMAs (4 independent acc chains).
#define FMA4(p,q,r,s) { \
    float bp = lane_bcast(av, p), bq = lane_bcast(av, q); \
    float br = lane_bcast(av, r), bs = lane_bcast(av, s); \
    acc0 = fmaf(et##p, bp, acc0); acc1 = fmaf(et##q, bq, acc1); \
    acc2 = fmaf(et##r, br, acc2); acc3 = fmaf(et##s, bs, acc3); }

#define DO_STEP(FV, MKV) { \
    float av = a; \
    float acc0 = 0.f, acc1 = 0.f, acc2 = 0.f, acc3 = 0.f; \
    FMA4(0,1,2,3)     FMA4(4,5,6,7)     FMA4(8,9,10,11)   FMA4(12,13,14,15)  \
    FMA4(16,17,18,19) FMA4(20,21,22,23) FMA4(24,25,26,27) FMA4(28,29,30,31)  \
    FMA4(32,33,34,35) FMA4(36,37,38,39) FMA4(40,41,42,43) FMA4(44,45,46,47)  \
    FMA4(48,49,50,51) FMA4(52,53,54,55) FMA4(56,57,58,59) FMA4(60,61,62,63)  \
    float s_ = (acc0 + acc1) + (acc2 + acc3); \
    float anew = s_ * __expf(FV); \
    a = ((MKV) != 0.0f) ? anew : a; }

// Forward algorithm in the probability domain. One wave per batch element;
// lane i owns state i and exp(trans[i,:]) in 64 pinned VGPRs. Broadcast of
// a[j] via v_readlane. Groups of 4 steps; feats+masks prefetched one group
// ahead (ring registers). Renorm once per group by a[1] (any wave-uniform
// positive scale is exact via offset += log(scale); lane1 is provably >0 for
// t>=1 since only row START is dead and only column END is zeroed).
__global__ __launch_bounds__(64, 1) void crf_forward_kernel(
    const float* __restrict__ feats,
    const float* __restrict__ trans,
    const float* __restrict__ masks,
    const int*   __restrict__ tags,
    float* __restrict__ out)
{
    const int b = blockIdx.x;
    const int i = threadIdx.x;

    const float* trow = trans + i * KK;
    DECL4(0,1,2,3)     DECL4(4,5,6,7)     DECL4(8,9,10,11)   DECL4(12,13,14,15)
    DECL4(16,17,18,19) DECL4(20,21,22,23) DECL4(24,25,26,27) DECL4(28,29,30,31)
    DECL4(32,33,34,35) DECL4(36,37,38,39) DECL4(40,41,42,43) DECL4(44,45,46,47)
    DECL4(48,49,50,51) DECL4(52,53,54,55) DECL4(56,57,58,59) DECL4(60,61,62,63)
    PIN4(0,1,2,3)     PIN4(4,5,6,7)     PIN4(8,9,10,11)   PIN4(12,13,14,15)
    PIN4(16,17,18,19) PIN4(20,21,22,23) PIN4(24,25,26,27) PIN4(28,29,30,31)
    PIN4(32,33,34,35) PIN4(36,37,38,39) PIN4(40,41,42,43) PIN4(44,45,46,47)
    PIN4(48,49,50,51) PIN4(52,53,54,55) PIN4(56,57,58,59) PIN4(60,61,62,63)

    float a = (i == START_TAG) ? 1.0f : 0.0f;  // exp(alpha0)
    float offset = 0.0f;                        // running log-scale

    const float* fb = feats + (size_t)b * TT * KK;
    const float* mb = masks + (size_t)b * TT;

    // prologue prefetch: steps t = 1..4
    float cf0 = fb[1 * KK + i], cf1 = fb[2 * KK + i];
    float cf2 = fb[3 * KK + i], cf3 = fb[4 * KK + i];
    float cm0 = mb[1], cm1 = mb[2], cm2 = mb[3], cm3 = mb[4];

    // groups t0 = 1,5,...,1021; last group's 4th step (t=1024) masked off
    for (int t0 = 1; t0 < TT; t0 += 4) {
        int p0 = (t0 + 4 < TT) ? t0 + 4 : TT - 1;
        int p1 = (t0 + 5 < TT) ? t0 + 5 : TT - 1;
        int p2 = (t0 + 6 < TT) ? t0 + 6 : TT - 1;
        int p3 = (t0 + 7 < TT) ? t0 + 7 : TT - 1;
        float nf0 = fb[p0 * KK + i], nf1 = fb[p1 * KK + i];
        float nf2 = fb[p2 * KK + i], nf3 = fb[p3 * KK + i];
        float nm0 = mb[p0], nm1 = mb[p1], nm2 = mb[p2], nm3 = mb[p3];

        DO_STEP(cf0, cm0)
        DO_STEP(cf1, cm1)
        DO_STEP(cf2, cm2)
        float m3 = (t0 + 3 < TT) ? cm3 : 0.0f;   // only last group clips
        DO_STEP(cf3, m3)

        // cheap renorm: scale by a[1] (wave-uniform, provably > 0)
        float a1 = fmaxf(lane_bcast(a, 1), 1e-37f);
        a *= __builtin_amdgcn_rcpf(a1);
        offset += __logf(a1);

        cf0 = nf0; cf1 = nf1; cf2 = nf2; cf3 = nf3;
        cm0 = nm0; cm1 = nm1; cm2 = nm2; cm3 = nm3;
    }

    // forward_score = offset + log(sum_j a_j)
    float s = a;
    #pragma unroll
    for (int off = 32; off >= 1; off >>= 1)
        s += __shfl_xor(s, off, 64);
    float fwd_score = offset + __logf(s);

    // ---- fused gold score: sum_t (trans[ct,pt] + feats[t,ct]) * mask[t] ----
    const int* tg = tags + b * TT;
    float g = 0.f;
    for (int t = 1 + i; t < TT; t += 64) {
        int ct = tg[t], pt = tg[t - 1];
        g += (trans[ct * KK + pt] + fb[t * KK + ct]) * mb[t];
    }
    #pragma unroll
    for (int off = 32; off >= 1; off >>= 1)
        g += __shfl_xor(g, off, 64);

    if (i == 0) atomicAdd(out, (fwd_score - g) * (1.0f / (float)BB));
}

extern "C" void kernel_launch(void* const* d_in, const int* in_sizes, int n_in,
                              void* d_out, int out_size, void* d_ws, size_t ws_size,
                              hipStream_t stream) {
    const float* feats = (const float*)d_in[0];
    const float* trans = (const float*)d_in[1];
    const int*   tags  = (const int*)d_in[2];
    const float* masks = (const float*)d_in[3];
    float* out = (float*)d_out;

    hipMemsetAsync(out, 0, sizeof(float), stream);  // atomicAdd accumulator
    crf_forward_kernel<<<BB, 64, 0, stream>>>(feats, trans, masks, tags, out);
}

// Round 5
// 368.305 us; speedup vs baseline: 2.0069x; 1.0495x over previous
//
#include <hip/hip_runtime.h>

#define KK 64
#define TT 1024
#define BB 256
#define START_TAG 0

__device__ __forceinline__ float lane_bcast(float v, int lane) {
    return __int_as_float(__builtin_amdgcn_readlane(__float_as_int(v), lane));
}

// 64 named scalars for the exp(trans) row, PINNED into VGPRs with opaque asm
// so the compiler cannot rematerialize exp(load(trow[j])) inside the loop.
#define DECL4(p,q,r,s) \
    float et##p = __expf(trow[p]), et##q = __expf(trow[q]), \
          et##r = __expf(trow[r]), et##s = __expf(trow[s]);

#define PIN4(p,q,r,s) \
    asm volatile("" : "+v"(et##p), "+v"(et##q), "+v"(et##r), "+v"(et##s));

// Batch 4 readlanes ahead of their 4 FMAs (4 independent acc chains).
#define FMA4(p,q,r,s) { \
    float bp = lane_bcast(av, p), bq = lane_bcast(av, q); \
    float br = lane_bcast(av, r), bs = lane_bcast(av, s); \
    acc0 = fmaf(et##p, bp, acc0); acc1 = fmaf(et##q, bq, acc1); \
    acc2 = fmaf(et##r, br, acc2); acc3 = fmaf(et##s, bs, acc3); }

#define DO_STEP(FV, MKV) { \
    float av = a; \
    float acc0 = 0.f, acc1 = 0.f, acc2 = 0.f, acc3 = 0.f; \
    FMA4(0,1,2,3)     FMA4(4,5,6,7)     FMA4(8,9,10,11)   FMA4(12,13,14,15)  \
    FMA4(16,17,18,19) FMA4(20,21,22,23) FMA4(24,25,26,27) FMA4(28,29,30,31)  \
    FMA4(32,33,34,35) FMA4(36,37,38,39) FMA4(40,41,42,43) FMA4(44,45,46,47)  \
    FMA4(48,49,50,51) FMA4(52,53,54,55) FMA4(56,57,58,59) FMA4(60,61,62,63)  \
    float s_ = (acc0 + acc1) + (acc2 + acc3); \
    float anew = s_ * __expf(FV); \
    a = ((MKV) != 0.0f) ? anew : a; }

// Forward algorithm in the probability domain. One wave per batch element;
// lane i owns state i and exp(trans[i,:]) in 64 pinned VGPRs. Broadcast of
// a[j] via v_readlane. Groups of 4 steps; feats+masks prefetched one group
// ahead. Renorm once per group by a[1] (any wave-uniform positive scale is
// exact via offset += log(scale)).
//
// amdgpu_waves_per_eu(1,1): grid is 256 blocks x 1 wave = 1 wave/CU
// structurally, so declare max occupancy 1 wave/EU. Without the explicit MAX
// the scheduler targets 8 waves/EU and spills et to scratch to fit 64 VGPRs
// (rounds 2-4 all allocated <=64 VGPRs for this reason).
__global__ __launch_bounds__(64)
__attribute__((amdgpu_waves_per_eu(1, 1)))
void crf_forward_kernel(
    const float* __restrict__ feats,
    const float* __restrict__ trans,
    const float* __restrict__ masks,
    const int*   __restrict__ tags,
    float* __restrict__ out)
{
    const int b = blockIdx.x;
    const int i = threadIdx.x;

    const float* trow = trans + i * KK;
    DECL4(0,1,2,3)     DECL4(4,5,6,7)     DECL4(8,9,10,11)   DECL4(12,13,14,15)
    DECL4(16,17,18,19) DECL4(20,21,22,23) DECL4(24,25,26,27) DECL4(28,29,30,31)
    DECL4(32,33,34,35) DECL4(36,37,38,39) DECL4(40,41,42,43) DECL4(44,45,46,47)
    DECL4(48,49,50,51) DECL4(52,53,54,55) DECL4(56,57,58,59) DECL4(60,61,62,63)
    PIN4(0,1,2,3)     PIN4(4,5,6,7)     PIN4(8,9,10,11)   PIN4(12,13,14,15)
    PIN4(16,17,18,19) PIN4(20,21,22,23) PIN4(24,25,26,27) PIN4(28,29,30,31)
    PIN4(32,33,34,35) PIN4(36,37,38,39) PIN4(40,41,42,43) PIN4(44,45,46,47)
    PIN4(48,49,50,51) PIN4(52,53,54,55) PIN4(56,57,58,59) PIN4(60,61,62,63)

    float a = (i == START_TAG) ? 1.0f : 0.0f;  // exp(alpha0)
    float offset = 0.0f;                        // running log-scale

    const float* fb = feats + (size_t)b * TT * KK;
    const float* mb = masks + (size_t)b * TT;

    // prologue prefetch: steps t = 1..4
    float cf0 = fb[1 * KK + i], cf1 = fb[2 * KK + i];
    float cf2 = fb[3 * KK + i], cf3 = fb[4 * KK + i];
    float cm0 = mb[1], cm1 = mb[2], cm2 = mb[3], cm3 = mb[4];

    // groups t0 = 1,5,...,1021; last group's 4th step (t=1024) masked off
    for (int t0 = 1; t0 < TT; t0 += 4) {
        int p0 = (t0 + 4 < TT) ? t0 + 4 : TT - 1;
        int p1 = (t0 + 5 < TT) ? t0 + 5 : TT - 1;
        int p2 = (t0 + 6 < TT) ? t0 + 6 : TT - 1;
        int p3 = (t0 + 7 < TT) ? t0 + 7 : TT - 1;
        float nf0 = fb[p0 * KK + i], nf1 = fb[p1 * KK + i];
        float nf2 = fb[p2 * KK + i], nf3 = fb[p3 * KK + i];
        float nm0 = mb[p0], nm1 = mb[p1], nm2 = mb[p2], nm3 = mb[p3];

        DO_STEP(cf0, cm0)
        DO_STEP(cf1, cm1)
        DO_STEP(cf2, cm2)
        float m3 = (t0 + 3 < TT) ? cm3 : 0.0f;   // only last group clips
        DO_STEP(cf3, m3)

        // cheap renorm: scale by a[1] (wave-uniform, provably > 0)
        float a1 = fmaxf(lane_bcast(a, 1), 1e-37f);
        a *= __builtin_amdgcn_rcpf(a1);
        offset += __logf(a1);

        cf0 = nf0; cf1 = nf1; cf2 = nf2; cf3 = nf3;
        cm0 = nm0; cm1 = nm1; cm2 = nm2; cm3 = nm3;
    }

    // forward_score = offset + log(sum_j a_j)
    float s = a;
    #pragma unroll
    for (int off = 32; off >= 1; off >>= 1)
        s += __shfl_xor(s, off, 64);
    float fwd_score = offset + __logf(s);

    // ---- fused gold score: sum_t (trans[ct,pt] + feats[t,ct]) * mask[t] ----
    const int* tg = tags + b * TT;
    float g = 0.f;
    for (int t = 1 + i; t < TT; t += 64) {
        int ct = tg[t], pt = tg[t - 1];
        g += (trans[ct * KK + pt] + fb[t * KK + ct]) * mb[t];
    }
    #pragma unroll
    for (int off = 32; off >= 1; off >>= 1)
        g += __shfl_xor(g, off, 64);

    if (i == 0) atomicAdd(out, (fwd_score - g) * (1.0f / (float)BB));
}

extern "C" void kernel_launch(void* const* d_in, const int* in_sizes, int n_in,
                              void* d_out, int out_size, void* d_ws, size_t ws_size,
                              hipStream_t stream) {
    const float* feats = (const float*)d_in[0];
    const float* trans = (const float*)d_in[1];
    const int*   tags  = (const int*)d_in[2];
    const float* masks = (const float*)d_in[3];
    float* out = (float*)d_out;

    hipMemsetAsync(out, 0, sizeof(float), stream);  // atomicAdd accumulator
    crf_forward_kernel<<<BB, 64, 0, stream>>>(feats, trans, masks, tags, out);
}